// Round 6
// baseline (163.440 us; speedup 1.0000x reference)
//
#include <hip/hip_runtime.h>
#include <math.h>

// Problem constants (from reference)
#define BB    2
#define TT    64
#define NN    128
#define TN    8192      // TT*NN
#define MM    16384     // BB*TN
#define CMAP  2048
#define CCOMP 32
#define FHW   256       // 16*16

// comp kernel split
#define CSPLIT 64
#define CRANGE 32       // CMAP / CSPLIT

// attention tiling (rank-3, scalar-uniform K loads, no LDS)
#define QPT    8        // q rows per thread
#define QTILE  2048     // 256 threads * QPT
#define NQT    8        // MM / QTILE (4 per batch)
#define KSPLIT 64
#define KRANGE 128      // TN / KSPLIT

#define NEG_LOG2E (-1.44269504088896340736f)

// workspace layout (float offsets)
#define OFF_CP    0                                  // CSPLIT*BB*FHW*CCOMP = 1048576
#define OFF_COMP  (OFF_CP + CSPLIT*BB*FHW*CCOMP)     // 16384
#define OFF_A     (OFF_COMP + BB*FHW*CCOMP)          // MM*4  (alpha',beta',gamma',pad)
#define OFF_X     (OFF_A + MM*4)                     // MM*2  (xr0,xr1)
#define OFF_P     (OFF_X + MM*2)                     // KSPLIT*MM*4 (S0,S1,S2,pad)
// total ~ 5.4M floats ~ 21.5 MB

__device__ __forceinline__ float fast_sigmoid(float v) {
    return __builtin_amdgcn_rcpf(1.0f + __expf(-v));
}
__device__ __forceinline__ float fast_tanh(float v) {
    return 1.0f - 2.0f * __builtin_amdgcn_rcpf(1.0f + __expf(2.0f * v));
}

// K1a: comp partials (no atomics). Cp[cs][(b*FHW+hw)*32+o]
__global__ void k_comp_p(const float* __restrict__ metadata,
                         const float* __restrict__ comp_w,
                         float* __restrict__ Cp) {
    const int b  = blockIdx.x;
    const int cs = blockIdx.y;
    const int hw = threadIdx.x;

    __shared__ float wcs[CRANGE][CCOMP];   // [c][o], 4 KB
    for (int i = threadIdx.x; i < CRANGE * CCOMP; i += 256) {
        int c = i / CCOMP, o = i % CCOMP;
        wcs[c][o] = comp_w[o * CMAP + cs * CRANGE + c];
    }
    __syncthreads();

    float acc[CCOMP];
#pragma unroll
    for (int o = 0; o < CCOMP; o++) acc[o] = 0.0f;

    const float* mb = metadata + ((size_t)b * CMAP + (size_t)cs * CRANGE) * FHW + hw;
#pragma unroll 4
    for (int c = 0; c < CRANGE; c++) {
        float m = mb[c * FHW];
#pragma unroll
        for (int o = 0; o < CCOMP; o++) acc[o] += m * wcs[c][o];
    }

    float* outp = Cp + (size_t)cs * (BB * FHW * CCOMP) + ((size_t)b * FHW + hw) * CCOMP;
#pragma unroll
    for (int o = 0; o < CCOMP; o += 4) {
        *(float4*)&outp[o] = make_float4(acc[o], acc[o + 1], acc[o + 2], acc[o + 3]);
    }
}

// K1b: reduce CSPLIT partials + bias -> comp_ws. 4 threads per output.
__global__ void k_comp_reduce(const float* __restrict__ Cp,
                              const float* __restrict__ comp_b,
                              float* __restrict__ comp_ws) {
    const int t = threadIdx.x;
    const int i = blockIdx.x * 64 + (t >> 2);
    const int r = t & 3;

    float s = 0.0f;
#pragma unroll
    for (int k = 0; k < CSPLIT / 4; k++) {
        s += Cp[(size_t)(r * (CSPLIT / 4) + k) * (BB * FHW * CCOMP) + i];
    }
    s += __shfl_xor(s, 1);
    s += __shfl_xor(s, 2);
    if (r == 0) comp_ws[i] = s + comp_b[i & (CCOMP - 1)];
}

// K2: per-token: PE + LSTM + bilinear sample + vf + Q -> (alpha,beta,gamma); xr
__global__ void k_token(const float* __restrict__ x,
                        const float* __restrict__ w_ih,
                        const float* __restrict__ b_ih,
                        const float* __restrict__ b_hh,
                        const float* __restrict__ fc_w,  const float* __restrict__ fc_b,
                        const float* __restrict__ fc2_w, const float* __restrict__ fc2_b,
                        const float* __restrict__ vf_w,  const float* __restrict__ vf_b,
                        const float* __restrict__ comp_ws,
                        float4* __restrict__ Aq, float2* __restrict__ Xr) {
    const int m = blockIdx.x * 64 + threadIdx.x;
    const int b = m >> 13;
    const int p = m & (TN - 1);
    const int t = p >> 7;

    const float px = x[(size_t)(b * 2 + 0) * TN + p];
    const float py = x[(size_t)(b * 2 + 1) * TN + p];

    const float xr0 = px + __sinf((float)t);
    const float xr1 = py + __cosf((float)t);
    Xr[m] = make_float2(xr0, xr1);

    // single-step LSTM, h0=c0=0
    float X[4];
#pragma unroll
    for (int j = 0; j < 4; j++) {
        float gi = xr0 * w_ih[(j)      * 2] + xr1 * w_ih[(j)      * 2 + 1] + b_ih[j]      + b_hh[j];
        float gg = xr0 * w_ih[(8 + j)  * 2] + xr1 * w_ih[(8 + j)  * 2 + 1] + b_ih[8 + j]  + b_hh[8 + j];
        float go = xr0 * w_ih[(12 + j) * 2] + xr1 * w_ih[(12 + j) * 2 + 1] + b_ih[12 + j] + b_hh[12 + j];
        float cst = fast_sigmoid(gi) * fast_tanh(gg);
        X[j] = fast_sigmoid(go) * fast_tanh(cst);
    }

    // bilinear grid-sample of comp (zeros padding, align_corners=False)
    float lc[CCOMP];
#pragma unroll
    for (int c = 0; c < CCOMP; c++) lc[c] = 0.0f;

    const float ix = px * (1.0f / 32.0f) - 0.5f;
    const float iy = py * (1.0f / 32.0f) - 0.5f;
    const float fx0 = floorf(ix), fy0 = floorf(iy);
    const float wx = ix - fx0, wy = iy - fy0;
    const int x0 = (int)fx0, y0 = (int)fy0;
    const float* cb = comp_ws + (size_t)b * FHW * CCOMP;

#pragma unroll
    for (int dy = 0; dy < 2; dy++) {
#pragma unroll
        for (int dx = 0; dx < 2; dx++) {
            int xx = x0 + dx, yy = y0 + dy;
            if (xx < 0 || xx > 15 || yy < 0 || yy > 15) continue;
            float w = (dy ? wy : 1.0f - wy) * (dx ? wx : 1.0f - wx);
            const float4* cp4 = (const float4*)(cb + (yy * 16 + xx) * CCOMP);
#pragma unroll
            for (int c4 = 0; c4 < CCOMP / 4; c4++) {
                float4 v = cp4[c4];
                lc[c4 * 4 + 0] += w * v.x;
                lc[c4 * 4 + 1] += w * v.y;
                lc[c4 * 4 + 2] += w * v.z;
                lc[c4 * 4 + 3] += w * v.w;
            }
        }
    }

    // vf
    float X2[4];
#pragma unroll
    for (int j = 0; j < 4; j++) {
        float a = vf_b[j];
#pragma unroll
        for (int k = 0; k < 4; k++) a += X[k] * vf_w[j * 36 + k];
#pragma unroll
        for (int c = 0; c < CCOMP; c++) a += lc[c] * vf_w[j * 36 + 4 + c];
        X2[j] = a;
    }

    // Q then rank-3 projection onto K's affine basis
    float al = 0.0f, be = 0.0f, ga = 0.0f;
#pragma unroll
    for (int d = 0; d < 8; d++) {
        float q = fc_b[d];
#pragma unroll
        for (int k = 0; k < 4; k++) q += X2[k] * fc_w[d * 4 + k];
        al += q * fc2_b[d];
        be += q * fc2_w[d * 2];
        ga += q * fc2_w[d * 2 + 1];
    }
    Aq[m] = make_float4(NEG_LOG2E * al, NEG_LOG2E * be, NEG_LOG2E * ga, 0.0f);
}

// K3: rank-3 partial attention, scalar-uniform k reads (no LDS, no barrier).
// grid (NQT, KSPLIT) = 512 blocks. Per thread: 8 q rows x 128 k rows.
// Xr[kbase+j] is wave-uniform -> s_load; 8 independent sigmoid chains/thread.
__global__ void __launch_bounds__(256) k_attn(const float4* __restrict__ Aq,
                                              const float2* __restrict__ Xr,
                                              float4* __restrict__ Pw) {
    const int tile = blockIdx.x;     // 0..7
    const int b  = tile >> 2;
    const int tq = tile & 3;
    const int ks = blockIdx.y;

    const int qb = b * TN + tq * QTILE + threadIdx.x;

    float al[QPT], be[QPT], ga[QPT], S0[QPT], S1[QPT], S2[QPT];
#pragma unroll
    for (int qi = 0; qi < QPT; qi++) {
        float4 A = Aq[qb + qi * 256];
        al[qi] = A.x; be[qi] = A.y; ga[qi] = A.z;
        S0[qi] = 0.0f; S1[qi] = 0.0f; S2[qi] = 0.0f;
    }

    const float2* __restrict__ xp = Xr + b * TN + ks * KRANGE;

#pragma unroll 4
    for (int j = 0; j < KRANGE; j++) {
        const float2 xv = xp[j];           // wave-uniform address -> SMEM
        const float x0 = xv.x, x1 = xv.y;
#pragma unroll
        for (int qi = 0; qi < QPT; qi++) {
            float e = __builtin_amdgcn_exp2f(al[qi] + be[qi] * x0 + ga[qi] * x1);
            float pr = __builtin_amdgcn_rcpf(1.0f + e);
            S0[qi] += pr;
            S1[qi] += pr * x0;
            S2[qi] += pr * x1;
        }
    }

#pragma unroll
    for (int qi = 0; qi < QPT; qi++) {
        Pw[(size_t)ks * MM + (qb + qi * 256)] = make_float4(S0[qi], S1[qi], S2[qi], 0.0f);
    }
}

// K4: reduce KSPLIT partials (4 threads/token), reconstruct via V's affine
// basis, threshold-ReLU + fcout + transpose. grid 256 blocks x 256 thr.
__global__ void k_out(const float4* __restrict__ Pw,
                      const float* __restrict__ fc3_w, const float* __restrict__ fc3_b,
                      const float* __restrict__ fcout_w,
                      const float* __restrict__ fcout_b,
                      float* __restrict__ y) {
    const int t = threadIdx.x;
    const int m = blockIdx.x * 64 + (t >> 2);
    const int r = t & 3;
    const int b = m >> 13;
    const int p = m & (TN - 1);

    float S0 = 0.0f, S1 = 0.0f, S2 = 0.0f;
#pragma unroll
    for (int k = 0; k < KSPLIT / 4; k++) {
        float4 pp = Pw[(size_t)(r * (KSPLIT / 4) + k) * MM + m];
        S0 += pp.x; S1 += pp.y; S2 += pp.z;
    }
    S0 += __shfl_xor(S0, 1); S0 += __shfl_xor(S0, 2);
    S1 += __shfl_xor(S1, 1); S1 += __shfl_xor(S1, 2);
    S2 += __shfl_xor(S2, 1); S2 += __shfl_xor(S2, 2);

    if (r == 0) {
        float f0 = fcout_b[0], f1 = fcout_b[1];
#pragma unroll
        for (int d = 0; d < 8; d++) {
            float v = S0 * fc3_b[d] + S1 * fc3_w[d * 2] + S2 * fc3_w[d * 2 + 1];
            v = (v > 0.5f) ? v : 0.0f;
            f0 += v * fcout_w[d];
            f1 += v * fcout_w[8 + d];
        }
        y[(size_t)(b * 2 + 0) * TN + p] = f0;
        y[(size_t)(b * 2 + 1) * TN + p] = f1;
    }
}

extern "C" void kernel_launch(void* const* d_in, const int* in_sizes, int n_in,
                              void* d_out, int out_size, void* d_ws, size_t ws_size,
                              hipStream_t stream) {
    const float* x        = (const float*)d_in[0];
    const float* metadata = (const float*)d_in[1];
    const float* w_ih     = (const float*)d_in[2];
    // d_in[3] = w_hh: unused (h0 = 0)
    const float* b_ih     = (const float*)d_in[4];
    const float* b_hh     = (const float*)d_in[5];
    const float* fc_w     = (const float*)d_in[6];
    const float* fc_b     = (const float*)d_in[7];
    const float* fc2_w    = (const float*)d_in[8];
    const float* fc2_b    = (const float*)d_in[9];
    const float* fc3_w    = (const float*)d_in[10];
    const float* fc3_b    = (const float*)d_in[11];
    const float* comp_w   = (const float*)d_in[12];
    const float* comp_b   = (const float*)d_in[13];
    const float* vf_w     = (const float*)d_in[14];
    const float* vf_b     = (const float*)d_in[15];
    const float* fcout_w  = (const float*)d_in[16];
    const float* fcout_b  = (const float*)d_in[17];

    float*  ws      = (float*)d_ws;
    float*  Cp      = ws + OFF_CP;
    float*  comp_ws = ws + OFF_COMP;
    float4* Aq      = (float4*)(ws + OFF_A);
    float2* Xr      = (float2*)(ws + OFF_X);
    float4* Pw      = (float4*)(ws + OFF_P);

    k_comp_p<<<dim3(BB, CSPLIT), 256, 0, stream>>>(metadata, comp_w, Cp);

    k_comp_reduce<<<256, 256, 0, stream>>>(Cp, comp_b, comp_ws);

    k_token<<<MM / 64, 64, 0, stream>>>(x, w_ih, b_ih, b_hh,
                                        fc_w, fc_b, fc2_w, fc2_b,
                                        vf_w, vf_b, comp_ws, Aq, Xr);

    k_attn<<<dim3(NQT, KSPLIT), 256, 0, stream>>>(Aq, Xr, Pw);

    k_out<<<256, 256, 0, stream>>>(Pw, fc3_w, fc3_b, fcout_w, fcout_b, (float*)d_out);
}